// Round 1
// baseline (851.100 us; speedup 1.0000x reference)
//
#include <hip/hip_runtime.h>
#include <stdint.h>

#define THRESH 0.5f
#define DECAY  0.2f
#define TSTEPS 5

#define B_        32
#define CONV_ELEMS (32*256*20*20)   // 3,276,800
#define RR        1152
#define CC        10
#define OO        16
#define PRIM_ELEMS (32*1152*8)      // 294,912
#define DIG_ELEMS  (32*1152*160)    // 5,898,240
#define MM        256
#define NN        1152
#define KK        20736
#define KSPLIT    8
#define KCHUNK    (KK/KSPLIT)       // 2592 = 81 * 32

typedef __attribute__((ext_vector_type(8))) short bf16x8;
typedef __attribute__((ext_vector_type(4))) float f32x4;
typedef __attribute__((ext_vector_type(8))) unsigned short u16x8;

__device__ __forceinline__ unsigned short f32_to_bf16(float f) {
    uint32_t u = __float_as_uint(f);
    uint32_t r = 0x7FFFu + ((u >> 16) & 1u);
    return (unsigned short)((u + r) >> 16);
}
__device__ __forceinline__ float bf16_to_f32(unsigned short h) {
    return __uint_as_float(((uint32_t)h) << 16);
}

__device__ __forceinline__ void async16(void* l, const void* g) {
    __builtin_amdgcn_global_load_lds(
        (const __attribute__((address_space(1))) uint32_t*)g,
        (__attribute__((address_space(3))) uint32_t*)l, 16, 0, 0);
}

// ---------------- init ----------------
__global__ void k_init_bij(float* bij) {
    int i = blockIdx.x * 256 + threadIdx.x;
    if (i < RR * CC) bij[i] = 1.0f / 1152.0f;
}

// ---------------- conv1 (once): conv_out = relu(conv2d(data, conv_w) + conv_b) ----------------
__global__ void k_conv1(const float* __restrict__ data, const float* __restrict__ cw,
                        const float* __restrict__ cb, float* __restrict__ out) {
    int e = blockIdx.x * 256 + threadIdx.x;
    if (e >= CONV_ELEMS) return;
    int x = e % 20, y = (e / 20) % 20, oc = (e / 400) % 256, b = e / 102400;
    const float* dp = data + b * 784 + y * 28 + x;
    const float* wp = cw + oc * 81;
    float s = 0.f;
    #pragma unroll
    for (int ky = 0; ky < 9; ++ky)
        #pragma unroll
        for (int kx = 0; kx < 9; ++kx)
            s += dp[ky * 28 + kx] * wp[ky * 9 + kx];
    out[e] = fmaxf(s + cb[oc], 0.f);
}

// ---------------- weight split: prim_w -> bf16 hi/lo, layout [oc][k] ----------------
__global__ void k_wsplit(const float* __restrict__ w, unsigned short* __restrict__ hi,
                         unsigned short* __restrict__ lo) {
    int e = blockIdx.x * 256 + threadIdx.x;
    if (e >= MM * KK) return;
    float f = w[e];
    unsigned short h = f32_to_bf16(f);
    hi[e] = h;
    lo[e] = f32_to_bf16(f - bf16_to_f32(h));
}

// ---------------- conv membrane update + spike (bf16) ----------------
__global__ void k_convmem(float* __restrict__ mem, const float* __restrict__ cout,
                          unsigned short* __restrict__ spk) {
    int e = blockIdx.x * 256 + threadIdx.x;
    if (e >= CONV_ELEMS) return;
    float m = mem[e];
    float ps = (m > THRESH) ? THRESH : 0.f;
    m = (m - ps) * DECAY + cout[e];
    mem[e] = m;
    spk[e] = (m > THRESH) ? (unsigned short)0x3F80 : (unsigned short)0;
}

// ---------------- im2col: Bt[n][k] bf16, n = b*36 + oy*6 + ox, k = ic*81 + ky*9 + kx ----------------
__global__ void k_im2col(const unsigned short* __restrict__ spk, unsigned short* __restrict__ Bt) {
    int t = blockIdx.x * 256 + threadIdx.x;
    if (t >= NN * (KK / 8)) return;
    int n = t / (KK / 8);
    int k0 = (t % (KK / 8)) * 8;
    int b = n / 36, pos = n % 36, oy = pos / 6, ox = pos % 6;
    u16x8 v;
    #pragma unroll
    for (int j = 0; j < 8; ++j) {
        int k = k0 + j;
        int ic = k / 81, r2 = k % 81, ky = r2 / 9, kx = r2 % 9;
        v[j] = spk[((b * 256 + ic) * 20 + (oy * 2 + ky)) * 20 + (ox * 2 + kx)];
    }
    *(u16x8*)(Bt + (size_t)n * KK + k0) = v;
}

// ---------------- split-K MFMA GEMM: Cp[ks][oc][n] = Ahi/lo[oc][k] * Bt[n][k] ----------------
__global__ __launch_bounds__(256) void k_gemm(const unsigned short* __restrict__ Ahi,
                                              const unsigned short* __restrict__ Alo,
                                              const unsigned short* __restrict__ Bt,
                                              float* __restrict__ Cp) {
    __shared__ unsigned short sA[2][64 * 32];
    __shared__ unsigned short sB[64 * 32];
    int tm = blockIdx.x;   // 0..3   (oc tiles of 64)
    int tn = blockIdx.y;   // 0..17  (n tiles of 64)
    int ks = blockIdx.z;   // 0..7   (K split)
    int tid = threadIdx.x;
    int row = tid >> 2;
    int cc  = (tid & 3) * 8;
    const int kbase = ks * KCHUNK;
    const unsigned short* gAh = Ahi + (tm * 64 + row) * KK + kbase + cc;
    const unsigned short* gAl = Alo + (tm * 64 + row) * KK + kbase + cc;
    const unsigned short* gB  = Bt  + (size_t)(tn * 64 + row) * KK + kbase + cc;
    unsigned short* lAh = &sA[0][tid * 8];
    unsigned short* lAl = &sA[1][tid * 8];
    unsigned short* lB  = &sB[tid * 8];

    int wid = tid >> 6, lane = tid & 63;
    int wr = wid >> 1, wc = wid & 1;
    int fr = lane & 15, kg = (lane >> 4) * 8;

    f32x4 acc[2][2] = {};
    for (int kk = 0; kk < KCHUNK; kk += 32) {
        async16(lAh, gAh + kk);
        async16(lAl, gAl + kk);
        async16(lB,  gB + kk);
        __syncthreads();
        bf16x8 ah[2], al[2], bv[2];
        #pragma unroll
        for (int i = 0; i < 2; ++i) {
            ah[i] = *(const bf16x8*)&sA[0][(wr * 32 + i * 16 + fr) * 32 + kg];
            al[i] = *(const bf16x8*)&sA[1][(wr * 32 + i * 16 + fr) * 32 + kg];
            bv[i] = *(const bf16x8*)&sB[(wc * 32 + i * 16 + fr) * 32 + kg];
        }
        #pragma unroll
        for (int i = 0; i < 2; ++i)
            #pragma unroll
            for (int j = 0; j < 2; ++j) {
                acc[i][j] = __builtin_amdgcn_mfma_f32_16x16x32_bf16(ah[i], bv[j], acc[i][j], 0, 0, 0);
                acc[i][j] = __builtin_amdgcn_mfma_f32_16x16x32_bf16(al[i], bv[j], acc[i][j], 0, 0, 0);
            }
        __syncthreads();
    }
    int colb = lane & 15, rb = (lane >> 4) * 4;
    float* Co = Cp + (size_t)ks * (MM * NN);
    #pragma unroll
    for (int i = 0; i < 2; ++i)
        #pragma unroll
        for (int j = 0; j < 2; ++j) {
            int gm = tm * 64 + wr * 32 + i * 16 + rb;
            int gn = tn * 64 + wc * 32 + j * 16 + colb;
            #pragma unroll
            for (int q = 0; q < 4; ++q)
                Co[(gm + q) * NN + gn] = acc[i][j][q];
        }
}

// ---------------- split-K reduce + prim membrane update ----------------
__global__ void k_primmem(const float* __restrict__ Cp, const float* __restrict__ pb,
                          float* __restrict__ pmem) {
    int e = blockIdx.x * 256 + threadIdx.x;
    if (e >= PRIM_ELEMS) return;
    int b = e / 9216, j = e % 9216;
    int oc = j / 36, pos = j % 36;
    int n = b * 36 + pos;
    float s = 0.f;
    #pragma unroll
    for (int ks = 0; ks < KSPLIT; ++ks) s += Cp[(size_t)ks * (MM * NN) + oc * NN + n];
    s += pb[oc];
    float m = pmem[e];
    float ps = (m > THRESH) ? THRESH : 0.f;
    pmem[e] = (m - ps) * DECAY + s;
}

// ---------------- dig pass 1: u_hat + dig_mem/spike + s_j partials + trace age ----------------
__global__ __launch_bounds__(160) void k_dig(const float* __restrict__ pmem,
                                             const float* __restrict__ W,
                                             const float* __restrict__ bias,
                                             const float* __restrict__ bij,
                                             float* __restrict__ dmem,
                                             uint8_t* __restrict__ age,
                                             float* __restrict__ sj) {
    __shared__ float sp[512];
    __shared__ float sb[640];
    int b = blockIdx.x, r0 = blockIdx.y * 64;
    int tid = threadIdx.x;
    for (int i = tid; i < 512; i += 160)
        sp[i] = (pmem[b * 9216 + r0 * 8 + i] > THRESH) ? 1.f : 0.f;
    for (int i = tid; i < 640; i += 160)
        sb[i] = bij[r0 * 10 + i];
    __syncthreads();
    int c = tid / 16, o = tid % 16;
    float bo = bias[o];
    float sacc = 0.f;
    int base = (b * 1152 + r0) * 160 + tid;
    for (int rr = 0; rr < 64; ++rr) {
        const float* wp = W + (((r0 + rr) * 10 + c) * 16 + o) * 8;
        const float* s8 = sp + rr * 8;
        float u = bo;
        #pragma unroll
        for (int i = 0; i < 8; ++i) u += wp[i] * s8[i];
        int idx = base + rr * 160;
        float m = dmem[idx];
        float ps = (m > THRESH) ? THRESH : 0.f;
        m = (m - ps) * DECAY + u;
        dmem[idx] = m;
        bool spk = m > THRESH;
        if (spk) sacc += sb[rr * 10 + c];
        uint8_t a = age[idx];
        age[idx] = spk ? (uint8_t)0 : (a == 255 ? (uint8_t)255 : (uint8_t)(a + 1));
    }
    atomicAdd(&sj[b * 160 + tid], sacc);
}

// ---------------- dig2 membrane + out_mem ----------------
__global__ void k_dig2(const float* __restrict__ sj, float* __restrict__ d2mem,
                       float* __restrict__ omem) {
    int e = blockIdx.x * 256 + threadIdx.x;
    if (e >= B_ * 160) return;
    float s = sj[e];
    float m = d2mem[e];
    float ps = (m > THRESH) ? THRESH : 0.f;
    d2mem[e] = (m - ps) * DECAY + s;
    omem[e] += s;
}

// ---------------- b_ij update: clip + 0.0008 * mean_b sum_o (trace-0.1)*d2s ----------------
__global__ void k_bij(const uint8_t* __restrict__ age, const float* __restrict__ d2mem,
                      float* __restrict__ bij) {
    int g = blockIdx.x * 256 + threadIdx.x;
    if (g >= RR * 160) return;
    int r = g / 160, co = g % 160, c = co / 16, o = co & 15;
    const float dtr = expf(-1.0f / 1.5f);
    float tab[5];
    tab[0] = 1.f;
    #pragma unroll
    for (int k = 1; k < 5; ++k) tab[k] = tab[k - 1] * dtr;
    float acc = 0.f;
    for (int b = 0; b < B_; ++b) {
        uint8_t a = age[(size_t)b * (RR * 160) + g];
        float tv = (a > 4) ? 0.f : tab[a];
        float d2 = (d2mem[b * 160 + co] > THRESH) ? 1.f : 0.f;
        acc += (tv - 0.1f) * d2;
    }
    #pragma unroll
    for (int off = 1; off < 16; off <<= 1) acc += __shfl_xor(acc, off);
    if (o == 0) {
        float bo = bij[r * 10 + c];
        bo = fminf(fmaxf(bo, -0.05f), 1.0f);
        bij[r * 10 + c] = bo + 0.0008f * (acc * (1.0f / 32.0f));
    }
}

// ---------------- final: classes = sqrt(sum_o (out_mem/T)^2) ----------------
__global__ void k_out(const float* __restrict__ omem, float* __restrict__ out) {
    int i = blockIdx.x * 64 + threadIdx.x;
    if (i >= B_ * CC) return;
    int b = i / 10, c = i % 10;
    float s = 0.f;
    #pragma unroll
    for (int o = 0; o < 16; ++o) {
        float v = omem[b * 160 + c * 16 + o] / 5.0f;
        s += v * v;
    }
    out[i] = sqrtf(s);
}

extern "C" void kernel_launch(void* const* d_in, const int* in_sizes, int n_in,
                              void* d_out, int out_size, void* d_ws, size_t ws_size,
                              hipStream_t stream) {
    const float* data   = (const float*)d_in[0];
    const float* conv_w = (const float*)d_in[1];
    const float* conv_b = (const float*)d_in[2];
    const float* prim_w = (const float*)d_in[3];
    const float* prim_b = (const float*)d_in[4];
    const float* W      = (const float*)d_in[5];
    const float* bias   = (const float*)d_in[6];
    float* out = (float*)d_out;

    char* ws = (char*)d_ws;
    size_t off = 0;
    auto alloc = [&](size_t bytes) {
        void* p = ws + off;
        off = (off + bytes + 255) & ~(size_t)255;
        return p;
    };
    float*          conv_out = (float*)alloc((size_t)CONV_ELEMS * 4);
    float*          conv_mem = (float*)alloc((size_t)CONV_ELEMS * 4);
    unsigned short* conv_spk = (unsigned short*)alloc((size_t)CONV_ELEMS * 2);
    float*          prim_mem = (float*)alloc((size_t)PRIM_ELEMS * 4);
    float*          dig_mem  = (float*)alloc((size_t)DIG_ELEMS * 4);
    float*          dig2_mem = (float*)alloc(5120 * 4);
    float*          out_mem  = (float*)alloc(5120 * 4);
    float*          sj       = (float*)alloc(5120 * 4);
    uint8_t*        age      = (uint8_t*)alloc(DIG_ELEMS);
    float*          bij      = (float*)alloc(RR * CC * 4);
    unsigned short* Ahi      = (unsigned short*)alloc((size_t)MM * KK * 2);
    unsigned short* Alo      = (unsigned short*)alloc((size_t)MM * KK * 2);
    unsigned short* Bt       = (unsigned short*)alloc((size_t)NN * KK * 2);
    float*          Cp       = (float*)alloc((size_t)KSPLIT * MM * NN * 4);

    hipMemsetAsync(conv_mem, 0, (size_t)CONV_ELEMS * 4, stream);
    hipMemsetAsync(prim_mem, 0, (size_t)PRIM_ELEMS * 4, stream);
    hipMemsetAsync(dig_mem, 0, (size_t)DIG_ELEMS * 4, stream);
    hipMemsetAsync(dig2_mem, 0, 5120 * 4, stream);
    hipMemsetAsync(out_mem, 0, 5120 * 4, stream);
    hipMemsetAsync(age, 0xFF, DIG_ELEMS, stream);

    k_init_bij<<<(RR * CC + 255) / 256, 256, 0, stream>>>(bij);
    k_conv1<<<(CONV_ELEMS + 255) / 256, 256, 0, stream>>>(data, conv_w, conv_b, conv_out);
    k_wsplit<<<(MM * KK + 255) / 256, 256, 0, stream>>>(prim_w, Ahi, Alo);

    for (int t = 0; t < TSTEPS; ++t) {
        k_convmem<<<(CONV_ELEMS + 255) / 256, 256, 0, stream>>>(conv_mem, conv_out, conv_spk);
        k_im2col<<<(NN * (KK / 8) + 255) / 256, 256, 0, stream>>>(conv_spk, Bt);
        dim3 gg(4, 18, KSPLIT);
        k_gemm<<<gg, 256, 0, stream>>>(Ahi, Alo, Bt, Cp);
        k_primmem<<<(PRIM_ELEMS + 255) / 256, 256, 0, stream>>>(Cp, prim_b, prim_mem);
        hipMemsetAsync(sj, 0, 5120 * 4, stream);
        dim3 gd(32, 18);
        k_dig<<<gd, 160, 0, stream>>>(prim_mem, W, bias, bij, dig_mem, age, sj);
        k_dig2<<<(5120 + 255) / 256, 256, 0, stream>>>(sj, dig2_mem, out_mem);
        k_bij<<<(RR * 160 + 255) / 256, 256, 0, stream>>>(age, dig2_mem, bij);
    }
    k_out<<<(B_ * CC + 63) / 64, 64, 0, stream>>>(out_mem, out);
}

// Round 2
// 771.912 us; speedup vs baseline: 1.1026x; 1.1026x over previous
//
#include <hip/hip_runtime.h>
#include <stdint.h>

#define THRESH 0.5f
#define DECAY  0.2f
#define TSTEPS 5

#define B_        32
#define CONV_ELEMS (32*256*20*20)   // 3,276,800
#define RR        1152
#define CC        10
#define OO        16
#define PRIM_ELEMS (32*1152*8)      // 294,912
#define DIG_ELEMS  (32*1152*160)    // 5,898,240
#define MM        256
#define NN        1152
#define KK        20736
#define KSPLIT    12
#define KCHUNK    (KK/KSPLIT)       // 1728 = 27 * 64
#define RCH       4
#define NBDIG     (RR/RCH)          // 288

typedef __attribute__((ext_vector_type(8))) short bf16x8;
typedef __attribute__((ext_vector_type(4))) float f32x4;
typedef __attribute__((ext_vector_type(8))) unsigned short u16x8;
typedef __attribute__((ext_vector_type(4))) unsigned short u16x4;

__device__ __forceinline__ unsigned short f32_to_bf16(float f) {
    uint32_t u = __float_as_uint(f);
    uint32_t r = 0x7FFFu + ((u >> 16) & 1u);
    return (unsigned short)((u + r) >> 16);
}
__device__ __forceinline__ float bf16_to_f32(unsigned short h) {
    return __uint_as_float(((uint32_t)h) << 16);
}

__device__ __forceinline__ void async16(void* l, const void* g) {
    __builtin_amdgcn_global_load_lds(
        (const __attribute__((address_space(1))) uint32_t*)g,
        (__attribute__((address_space(3))) uint32_t*)l, 16, 0, 0);
}

// ---------------- init ----------------
__global__ void k_init_bij(float* bij) {
    int i = blockIdx.x * 256 + threadIdx.x;
    if (i < RR * CC) bij[i] = 1.0f / 1152.0f;
}

// ---------------- conv1 (once): LDS-tiled, row-strip per thread ----------------
__global__ __launch_bounds__(320) void k_conv1(const float* __restrict__ data,
                                               const float* __restrict__ cw,
                                               const float* __restrict__ cb,
                                               float* __restrict__ out) {
    __shared__ float sdat[784];
    __shared__ float swt[1296];
    int b = blockIdx.x, og = blockIdx.y;   // og: 16-oc group
    int tid = threadIdx.x;
    for (int i = tid; i < 196; i += 320)
        ((f32x4*)sdat)[i] = ((const f32x4*)(data + b * 784))[i];
    for (int i = tid; i < 324; i += 320)
        ((f32x4*)swt)[i] = ((const f32x4*)(cw + og * 1296))[i];
    __syncthreads();
    int ocl = tid / 20, y = tid % 20;
    float acc[20];
    #pragma unroll
    for (int x = 0; x < 20; ++x) acc[x] = 0.f;
    const float* wb = &swt[ocl * 81];
    #pragma unroll
    for (int ky = 0; ky < 9; ++ky) {
        const float* dr = &sdat[(y + ky) * 28];
        float d[28];
        #pragma unroll
        for (int t4 = 0; t4 < 7; ++t4) {
            f32x4 v = ((const f32x4*)dr)[t4];
            d[t4 * 4 + 0] = v.x; d[t4 * 4 + 1] = v.y;
            d[t4 * 4 + 2] = v.z; d[t4 * 4 + 3] = v.w;
        }
        float w[9];
        #pragma unroll
        for (int q = 0; q < 9; ++q) w[q] = wb[ky * 9 + q];
        #pragma unroll
        for (int kx = 0; kx < 9; ++kx)
            #pragma unroll
            for (int x = 0; x < 20; ++x)
                acc[x] += d[x + kx] * w[kx];
    }
    float bias = cb[og * 16 + ocl];
    float* op = out + (((size_t)b * 256 + og * 16 + ocl) * 20 + y) * 20;
    #pragma unroll
    for (int t4 = 0; t4 < 5; ++t4) {
        f32x4 v;
        v.x = fmaxf(acc[t4 * 4 + 0] + bias, 0.f);
        v.y = fmaxf(acc[t4 * 4 + 1] + bias, 0.f);
        v.z = fmaxf(acc[t4 * 4 + 2] + bias, 0.f);
        v.w = fmaxf(acc[t4 * 4 + 3] + bias, 0.f);
        ((f32x4*)op)[t4] = v;
    }
}

// ---------------- weight split: prim_w -> bf16 hi/lo, layout [oc][k] ----------------
__global__ void k_wsplit(const float* __restrict__ w, unsigned short* __restrict__ hi,
                         unsigned short* __restrict__ lo) {
    int e = blockIdx.x * 256 + threadIdx.x;
    if (e >= MM * KK) return;
    float f = w[e];
    unsigned short h = f32_to_bf16(f);
    hi[e] = h;
    lo[e] = f32_to_bf16(f - bf16_to_f32(h));
}

// ---------------- conv membrane update + spike (bf16), float4 ----------------
__global__ void k_convmem(float* __restrict__ mem, const float* __restrict__ cout,
                          unsigned short* __restrict__ spk) {
    int i = blockIdx.x * 256 + threadIdx.x;
    if (i >= CONV_ELEMS / 4) return;
    f32x4 m = ((f32x4*)mem)[i];
    f32x4 c = ((const f32x4*)cout)[i];
    u16x4 sp;
    #pragma unroll
    for (int j = 0; j < 4; ++j) {
        float mv = m[j];
        float ps = (mv > THRESH) ? THRESH : 0.f;
        mv = (mv - ps) * DECAY + c[j];
        m[j] = mv;
        sp[j] = (mv > THRESH) ? (unsigned short)0x3F80 : (unsigned short)0;
    }
    ((f32x4*)mem)[i] = m;
    ((u16x4*)spk)[i] = sp;
}

// ---------------- im2col: Bt[n][k] bf16 ----------------
__global__ void k_im2col(const unsigned short* __restrict__ spk, unsigned short* __restrict__ Bt) {
    int t = blockIdx.x * 256 + threadIdx.x;
    if (t >= NN * (KK / 8)) return;
    int n = t / (KK / 8);
    int k0 = (t % (KK / 8)) * 8;
    int b = n / 36, pos = n % 36, oy = pos / 6, ox = pos % 6;
    u16x8 v;
    #pragma unroll
    for (int j = 0; j < 8; ++j) {
        int k = k0 + j;
        int ic = k / 81, r2 = k % 81, ky = r2 / 9, kx = r2 % 9;
        v[j] = spk[((b * 256 + ic) * 20 + (oy * 2 + ky)) * 20 + (ox * 2 + kx)];
    }
    *(u16x8*)(Bt + (size_t)n * KK + k0) = v;
}

// ---------------- split-K MFMA GEMM, BK=64, XOR-swizzled LDS ----------------
__global__ __launch_bounds__(256) void k_gemm(const unsigned short* __restrict__ Ahi,
                                              const unsigned short* __restrict__ Alo,
                                              const unsigned short* __restrict__ Bt,
                                              float* __restrict__ Cp) {
    __shared__ unsigned short sAh[64 * 64];
    __shared__ unsigned short sAl[64 * 64];
    __shared__ unsigned short sB[64 * 64];
    int tm = blockIdx.x;   // 0..3
    int tn = blockIdx.y;   // 0..17
    int ks = blockIdx.z;   // 0..11
    int tid = threadIdx.x;
    const int kbase = ks * KCHUNK;

    // staging: two passes of 256 lanes; linear LDS dest, pre-swizzled global source
    int idx0 = tid, idx1 = tid + 256;
    int r0 = idx0 >> 3, r1 = idx1 >> 3;
    int e0 = ((((idx0 & 7) << 4) ^ ((r0 & 7) << 4)) >> 1);  // logical elem col
    int e1 = ((((idx1 & 7) << 4) ^ ((r1 & 7) << 4)) >> 1);
    const unsigned short* gAh0 = Ahi + (size_t)(tm * 64 + r0) * KK + kbase + e0;
    const unsigned short* gAh1 = Ahi + (size_t)(tm * 64 + r1) * KK + kbase + e1;
    const unsigned short* gAl0 = Alo + (size_t)(tm * 64 + r0) * KK + kbase + e0;
    const unsigned short* gAl1 = Alo + (size_t)(tm * 64 + r1) * KK + kbase + e1;
    const unsigned short* gB0  = Bt  + (size_t)(tn * 64 + r0) * KK + kbase + e0;
    const unsigned short* gB1  = Bt  + (size_t)(tn * 64 + r1) * KK + kbase + e1;
    unsigned short* dAh0 = &sAh[idx0 * 8]; unsigned short* dAh1 = &sAh[idx1 * 8];
    unsigned short* dAl0 = &sAl[idx0 * 8]; unsigned short* dAl1 = &sAl[idx1 * 8];
    unsigned short* dB0  = &sB[idx0 * 8];  unsigned short* dB1  = &sB[idx1 * 8];

    int wid = tid >> 6, lane = tid & 63;
    int wr = wid >> 1, wc = wid & 1;
    int fr = lane & 15, kg = (lane >> 4) * 8;

    // precomputed swizzled fragment offsets (elems)
    int offA[2][2], offB[2][2];
    #pragma unroll
    for (int i = 0; i < 2; ++i) {
        int ra = wr * 32 + i * 16 + fr;
        int rb = wc * 32 + i * 16 + fr;
        #pragma unroll
        for (int k2 = 0; k2 < 2; ++k2) {
            offA[i][k2] = ra * 64 + ((k2 * 32 + kg) ^ ((ra & 7) << 3));
            offB[i][k2] = rb * 64 + ((k2 * 32 + kg) ^ ((rb & 7) << 3));
        }
    }

    f32x4 acc[2][2] = {};
    for (int kk = 0; kk < KCHUNK; kk += 64) {
        async16(dAh0, gAh0 + kk); async16(dAh1, gAh1 + kk);
        async16(dAl0, gAl0 + kk); async16(dAl1, gAl1 + kk);
        async16(dB0,  gB0 + kk);  async16(dB1,  gB1 + kk);
        __syncthreads();
        bf16x8 ah[2][2], al[2][2], bv[2][2];
        #pragma unroll
        for (int i = 0; i < 2; ++i)
            #pragma unroll
            for (int k2 = 0; k2 < 2; ++k2) {
                ah[i][k2] = *(const bf16x8*)&sAh[offA[i][k2]];
                al[i][k2] = *(const bf16x8*)&sAl[offA[i][k2]];
                bv[i][k2] = *(const bf16x8*)&sB[offB[i][k2]];
            }
        #pragma unroll
        for (int k2 = 0; k2 < 2; ++k2)
            #pragma unroll
            for (int i = 0; i < 2; ++i)
                #pragma unroll
                for (int j = 0; j < 2; ++j) {
                    acc[i][j] = __builtin_amdgcn_mfma_f32_16x16x32_bf16(ah[i][k2], bv[j][k2], acc[i][j], 0, 0, 0);
                    acc[i][j] = __builtin_amdgcn_mfma_f32_16x16x32_bf16(al[i][k2], bv[j][k2], acc[i][j], 0, 0, 0);
                }
        __syncthreads();
    }
    int colb = lane & 15, rb4 = (lane >> 4) * 4;
    float* Co = Cp + (size_t)ks * (MM * NN);
    #pragma unroll
    for (int i = 0; i < 2; ++i)
        #pragma unroll
        for (int j = 0; j < 2; ++j) {
            int gm = tm * 64 + wr * 32 + i * 16 + rb4;
            int gn = tn * 64 + wc * 32 + j * 16 + colb;
            #pragma unroll
            for (int q = 0; q < 4; ++q)
                Co[(size_t)(gm + q) * NN + gn] = acc[i][j][q];
        }
}

// ---------------- split-K reduce + prim membrane update ----------------
__global__ void k_primmem(const float* __restrict__ Cp, const float* __restrict__ pb,
                          float* __restrict__ pmem) {
    int e = blockIdx.x * 256 + threadIdx.x;
    if (e >= PRIM_ELEMS) return;
    int b = e / 9216, j = e % 9216;
    int oc = j / 36, pos = j % 36;
    int n = b * 36 + pos;
    float s = 0.f;
    #pragma unroll
    for (int ks = 0; ks < KSPLIT; ++ks) s += Cp[(size_t)ks * (MM * NN) + oc * NN + n];
    s += pb[oc];
    float m = pmem[e];
    float ps = (m > THRESH) ? THRESH : 0.f;
    pmem[e] = (m - ps) * DECAY + s;
}

// ---------------- dig: all-batch per block, W read once, no atomics ----------------
__global__ __launch_bounds__(320) void k_dig(const float* __restrict__ pmem,
                                             const float* __restrict__ W,
                                             const float* __restrict__ bias,
                                             const float* __restrict__ bij,
                                             float* __restrict__ dmem,
                                             uint8_t* __restrict__ age,
                                             float* __restrict__ sjp) {
    __shared__ float ps[RCH * 32 * 8];   // [r][b][i] -> (r*32+b)*8+i
    int blk = blockIdx.x;
    int r0 = blk * RCH;
    int tid = threadIdx.x;
    for (int l = tid; l < RCH * 32 * 8; l += 320) {
        int b = l >> 5, j = l & 31;                 // j = r*8 + i
        float v = pmem[b * 9216 + r0 * 8 + j];
        ps[(j >> 3) * 256 + b * 8 + (j & 7)] = (v > THRESH) ? 1.f : 0.f;
    }
    __syncthreads();
    int co = tid % 160, bh = tid / 160;
    int c = co >> 4, o = co & 15;
    float bo = bias[o];
    float sacc[16];
    #pragma unroll
    for (int bb = 0; bb < 16; ++bb) sacc[bb] = 0.f;
    for (int r = 0; r < RCH; ++r) {
        int rr = r0 + r;
        const float* wp = W + ((size_t)((rr * 10 + c) * 16 + o)) * 8;
        f32x4 w0 = *(const f32x4*)wp;
        f32x4 w1 = *(const f32x4*)(wp + 4);
        float bv = bij[rr * 10 + c];
        #pragma unroll
        for (int bb = 0; bb < 16; ++bb) {
            int b = bh * 16 + bb;
            const float* p8 = &ps[(r * 32 + b) * 8];
            f32x4 pa = *(const f32x4*)p8;
            f32x4 pc = *(const f32x4*)(p8 + 4);
            float u = bo + w0.x * pa.x + w0.y * pa.y + w0.z * pa.z + w0.w * pa.w
                         + w1.x * pc.x + w1.y * pc.y + w1.z * pc.z + w1.w * pc.w;
            size_t idx = ((size_t)(b * 1152 + rr)) * 160 + co;
            float m = dmem[idx];
            float psv = (m > THRESH) ? THRESH : 0.f;
            m = (m - psv) * DECAY + u;
            dmem[idx] = m;
            bool s = m > THRESH;
            if (s) sacc[bb] += bv;
            uint8_t a = age[idx];
            age[idx] = s ? (uint8_t)0 : (a == 255 ? (uint8_t)255 : (uint8_t)(a + 1));
        }
    }
    #pragma unroll
    for (int bb = 0; bb < 16; ++bb)
        sjp[(size_t)blk * 5120 + (bh * 16 + bb) * 160 + co] = sacc[bb];
}

// ---------------- dig2: reduce sjp + membrane + out_mem ----------------
__global__ void k_dig2(const float* __restrict__ sjp, float* __restrict__ d2mem,
                       float* __restrict__ omem) {
    int e = blockIdx.x * 256 + threadIdx.x;
    if (e >= B_ * 160) return;
    float s = 0.f;
    #pragma unroll 8
    for (int k = 0; k < NBDIG; ++k) s += sjp[(size_t)k * 5120 + e];
    float m = d2mem[e];
    float ps = (m > THRESH) ? THRESH : 0.f;
    d2mem[e] = (m - ps) * DECAY + s;
    omem[e] += s;
}

// ---------------- b_ij update ----------------
__global__ void k_bij(const uint8_t* __restrict__ age, const float* __restrict__ d2mem,
                      float* __restrict__ bij) {
    int g = blockIdx.x * 256 + threadIdx.x;
    if (g >= RR * 160) return;
    int r = g / 160, co = g % 160, c = co / 16, o = co & 15;
    const float dtr = expf(-1.0f / 1.5f);
    float tab[5];
    tab[0] = 1.f;
    #pragma unroll
    for (int k = 1; k < 5; ++k) tab[k] = tab[k - 1] * dtr;
    float acc = 0.f;
    for (int b = 0; b < B_; ++b) {
        uint8_t a = age[(size_t)b * (RR * 160) + g];
        float tv = (a > 4) ? 0.f : tab[a];
        float d2 = (d2mem[b * 160 + co] > THRESH) ? 1.f : 0.f;
        acc += (tv - 0.1f) * d2;
    }
    #pragma unroll
    for (int off = 1; off < 16; off <<= 1) acc += __shfl_xor(acc, off);
    if (o == 0) {
        float bo = bij[r * 10 + c];
        bo = fminf(fmaxf(bo, -0.05f), 1.0f);
        bij[r * 10 + c] = bo + 0.0008f * (acc * (1.0f / 32.0f));
    }
}

// ---------------- final: classes ----------------
__global__ void k_out(const float* __restrict__ omem, float* __restrict__ out) {
    int i = blockIdx.x * 64 + threadIdx.x;
    if (i >= B_ * CC) return;
    int b = i / 10, c = i % 10;
    float s = 0.f;
    #pragma unroll
    for (int o = 0; o < 16; ++o) {
        float v = omem[b * 160 + c * 16 + o] / 5.0f;
        s += v * v;
    }
    out[i] = sqrtf(s);
}

extern "C" void kernel_launch(void* const* d_in, const int* in_sizes, int n_in,
                              void* d_out, int out_size, void* d_ws, size_t ws_size,
                              hipStream_t stream) {
    const float* data   = (const float*)d_in[0];
    const float* conv_w = (const float*)d_in[1];
    const float* conv_b = (const float*)d_in[2];
    const float* prim_w = (const float*)d_in[3];
    const float* prim_b = (const float*)d_in[4];
    const float* W      = (const float*)d_in[5];
    const float* bias   = (const float*)d_in[6];
    float* out = (float*)d_out;

    char* ws = (char*)d_ws;
    size_t off = 0;
    auto alloc = [&](size_t bytes) {
        void* p = ws + off;
        off = (off + bytes + 255) & ~(size_t)255;
        return p;
    };
    float*          conv_out = (float*)alloc((size_t)CONV_ELEMS * 4);
    float*          conv_mem = (float*)alloc((size_t)CONV_ELEMS * 4);
    unsigned short* conv_spk = (unsigned short*)alloc((size_t)CONV_ELEMS * 2);
    float*          prim_mem = (float*)alloc((size_t)PRIM_ELEMS * 4);
    float*          dig_mem  = (float*)alloc((size_t)DIG_ELEMS * 4);
    float*          dig2_mem = (float*)alloc(5120 * 4);
    float*          out_mem  = (float*)alloc(5120 * 4);
    float*          sjp      = (float*)alloc((size_t)NBDIG * 5120 * 4);
    uint8_t*        age      = (uint8_t*)alloc(DIG_ELEMS);
    float*          bij      = (float*)alloc(RR * CC * 4);
    unsigned short* Ahi      = (unsigned short*)alloc((size_t)MM * KK * 2);
    unsigned short* Alo      = (unsigned short*)alloc((size_t)MM * KK * 2);
    unsigned short* Bt       = (unsigned short*)alloc((size_t)NN * KK * 2);
    float*          Cp       = (float*)alloc((size_t)KSPLIT * MM * NN * 4);

    hipMemsetAsync(conv_mem, 0, (size_t)CONV_ELEMS * 4, stream);
    hipMemsetAsync(prim_mem, 0, (size_t)PRIM_ELEMS * 4, stream);
    hipMemsetAsync(dig_mem, 0, (size_t)DIG_ELEMS * 4, stream);
    hipMemsetAsync(dig2_mem, 0, 5120 * 4, stream);
    hipMemsetAsync(out_mem, 0, 5120 * 4, stream);
    hipMemsetAsync(age, 0xFF, DIG_ELEMS, stream);

    k_init_bij<<<(RR * CC + 255) / 256, 256, 0, stream>>>(bij);
    k_conv1<<<dim3(32, 16), 320, 0, stream>>>(data, conv_w, conv_b, conv_out);
    k_wsplit<<<(MM * KK + 255) / 256, 256, 0, stream>>>(prim_w, Ahi, Alo);

    for (int t = 0; t < TSTEPS; ++t) {
        k_convmem<<<(CONV_ELEMS / 4 + 255) / 256, 256, 0, stream>>>(conv_mem, conv_out, conv_spk);
        k_im2col<<<(NN * (KK / 8) + 255) / 256, 256, 0, stream>>>(conv_spk, Bt);
        dim3 gg(4, 18, KSPLIT);
        k_gemm<<<gg, 256, 0, stream>>>(Ahi, Alo, Bt, Cp);
        k_primmem<<<(PRIM_ELEMS + 255) / 256, 256, 0, stream>>>(Cp, prim_b, prim_mem);
        k_dig<<<NBDIG, 320, 0, stream>>>(prim_mem, W, bias, bij, dig_mem, age, sjp);
        k_dig2<<<(5120 + 255) / 256, 256, 0, stream>>>(sjp, dig2_mem, out_mem);
        k_bij<<<(RR * 160 + 255) / 256, 256, 0, stream>>>(age, dig2_mem, bij);
    }
    k_out<<<(B_ * CC + 63) / 64, 64, 0, stream>>>(out_mem, out);
}

// Round 3
// 442.334 us; speedup vs baseline: 1.9241x; 1.7451x over previous
//
#include <hip/hip_runtime.h>
#include <stdint.h>

#define THRESH 0.5f
#define DECAY  0.2f
#define TSTEPS 5

#define B_        32
#define CONV_ELEMS (32*256*20*20)   // 3,276,800  (NHWC: [b][y][x][ic])
#define RR        1152
#define CC        10
#define OO        16
#define PRIM_ELEMS (32*1152*8)      // 294,912
#define DIG_ELEMS  (32*1152*160)    // 5,898,240
#define MM        256
#define NN        1152
#define KK        20736             // 81 windows * 256 ic, k' = kw*256+ic
#define KSPLIT    18
#define NCHUNK    18                // 64-elem chunks per ks (18*18*64 = 20736)

typedef __attribute__((ext_vector_type(8))) short bf16x8;
typedef __attribute__((ext_vector_type(4))) float f32x4;
typedef __attribute__((ext_vector_type(4))) unsigned short u16x4;

__device__ __forceinline__ unsigned short f32_to_bf16(float f) {
    uint32_t u = __float_as_uint(f);
    uint32_t r = 0x7FFFu + ((u >> 16) & 1u);
    return (unsigned short)((u + r) >> 16);
}
__device__ __forceinline__ float bf16_to_f32(unsigned short h) {
    return __uint_as_float(((uint32_t)h) << 16);
}

__device__ __forceinline__ void async16(void* l, const void* g) {
    __builtin_amdgcn_global_load_lds(
        (const __attribute__((address_space(1))) uint32_t*)g,
        (__attribute__((address_space(3))) uint32_t*)l, 16, 0, 0);
}

// ---------------- init ----------------
__global__ void k_init_bij(float* bij) {
    int i = blockIdx.x * 256 + threadIdx.x;
    if (i < RR * CC) bij[i] = 1.0f / 1152.0f;
}

// ---------------- conv1 (once): compute NCHW-style, emit NHWC via LDS transpose ----------------
__global__ __launch_bounds__(320) void k_conv1(const float* __restrict__ data,
                                               const float* __restrict__ cw,
                                               const float* __restrict__ cb,
                                               float* __restrict__ out) {
    __shared__ float sdat[784];
    __shared__ float swt[1296];
    __shared__ float sout[20 * 333];   // [y][x*16+ocl], row pad 333 (13 mod 32 -> conflict-free)
    int b = blockIdx.x, og = blockIdx.y;   // og: 16-oc group
    int tid = threadIdx.x;
    for (int i = tid; i < 196; i += 320)
        ((f32x4*)sdat)[i] = ((const f32x4*)(data + b * 784))[i];
    for (int i = tid; i < 324; i += 320)
        ((f32x4*)swt)[i] = ((const f32x4*)(cw + og * 1296))[i];
    __syncthreads();
    int ocl = tid / 20, y = tid % 20;
    float acc[20];
    #pragma unroll
    for (int x = 0; x < 20; ++x) acc[x] = 0.f;
    const float* wb = &swt[ocl * 81];
    #pragma unroll
    for (int ky = 0; ky < 9; ++ky) {
        const float* dr = &sdat[(y + ky) * 28];
        float d[28];
        #pragma unroll
        for (int t4 = 0; t4 < 7; ++t4) {
            f32x4 v = ((const f32x4*)dr)[t4];
            d[t4 * 4 + 0] = v.x; d[t4 * 4 + 1] = v.y;
            d[t4 * 4 + 2] = v.z; d[t4 * 4 + 3] = v.w;
        }
        float w[9];
        #pragma unroll
        for (int q = 0; q < 9; ++q) w[q] = wb[ky * 9 + q];
        #pragma unroll
        for (int kx = 0; kx < 9; ++kx)
            #pragma unroll
            for (int x = 0; x < 20; ++x)
                acc[x] += d[x + kx] * w[kx];
    }
    float bias = cb[og * 16 + ocl];
    #pragma unroll
    for (int x = 0; x < 20; ++x)
        sout[y * 333 + x * 16 + ocl] = fmaxf(acc[x] + bias, 0.f);
    __syncthreads();
    const size_t base = (size_t)b * 102400 + og * 16;
    for (int f = tid; f < 6400; f += 320) {
        int yy = f / 320, rem = f % 320;
        out[base + (size_t)(f >> 4) * 256 + (f & 15)] = sout[yy * 333 + rem];
    }
}

// ---------------- weight split+relayout (once): A'[oc][kw*256+ic] bf16 hi/lo ----------------
__global__ __launch_bounds__(256) void k_wsplit(const float* __restrict__ w,
                                                unsigned short* __restrict__ hi,
                                                unsigned short* __restrict__ lo) {
    int oc = blockIdx.x, ic = threadIdx.x;
    const float* src = w + (size_t)oc * 20736 + ic * 81;   // prim_w[oc][ic][kw]
    unsigned short* dh = hi + (size_t)oc * 20736 + ic;
    unsigned short* dl = lo + (size_t)oc * 20736 + ic;
    for (int kw = 0; kw < 81; ++kw) {
        float f = src[kw];
        unsigned short h = f32_to_bf16(f);
        dh[kw * 256] = h;
        dl[kw * 256] = f32_to_bf16(f - bf16_to_f32(h));
    }
}

// ---------------- conv membrane update + spike (elementwise, NHWC) ----------------
__global__ void k_convmem(float* __restrict__ mem, const float* __restrict__ cout,
                          unsigned short* __restrict__ spk) {
    int i = blockIdx.x * 256 + threadIdx.x;
    if (i >= CONV_ELEMS / 4) return;
    f32x4 m = ((f32x4*)mem)[i];
    f32x4 c = ((const f32x4*)cout)[i];
    u16x4 sp;
    #pragma unroll
    for (int j = 0; j < 4; ++j) {
        float mv = m[j];
        float ps = (mv > THRESH) ? THRESH : 0.f;
        mv = (mv - ps) * DECAY + c[j];
        m[j] = mv;
        sp[j] = (mv > THRESH) ? (unsigned short)0x3F80 : (unsigned short)0;
    }
    ((f32x4*)mem)[i] = m;
    ((u16x4*)spk)[i] = sp;
}

// ---------------- fused-B split-K MFMA GEMM: Cp[ks][oc][n] ----------------
// B-tile staged straight from NHWC spk (no im2col). XCD-bijective block decode.
__global__ __launch_bounds__(256) void k_gemm(const unsigned short* __restrict__ Ahi,
                                              const unsigned short* __restrict__ Alo,
                                              const unsigned short* __restrict__ spk,
                                              float* __restrict__ Cp) {
    __shared__ unsigned short sAh[64 * 64];
    __shared__ unsigned short sAl[64 * 64];
    __shared__ unsigned short sB[64 * 64];
    int bid = blockIdx.x;
    int slot = bid & 7, j = bid >> 3;
    int tm = slot & 3;                    // all blocks sharing (tm,ks) share bid%8 -> same XCD
    int tn = j / 9;
    int ks = (slot >> 2) + 2 * (j % 9);
    int tid = threadIdx.x;

    int idx0 = tid, idx1 = tid + 256;
    int r0 = idx0 >> 3, r1 = idx1 >> 3;
    int e0 = ((idx0 & 7) ^ (r0 & 7)) << 3;   // pre-swizzled source elem col
    int e1 = ((idx1 & 7) ^ (r1 & 7)) << 3;
    const unsigned short* gAh0 = Ahi + (size_t)(tm * 64 + r0) * KK + ks * (NCHUNK * 64) + e0;
    const unsigned short* gAh1 = Ahi + (size_t)(tm * 64 + r1) * KK + ks * (NCHUNK * 64) + e1;
    const unsigned short* gAl0 = Alo + (size_t)(tm * 64 + r0) * KK + ks * (NCHUNK * 64) + e0;
    const unsigned short* gAl1 = Alo + (size_t)(tm * 64 + r1) * KK + ks * (NCHUNK * 64) + e1;
    // B row bases in NHWC spk: n -> (b, oy, ox)
    int n0 = tn * 64 + r0, n1 = tn * 64 + r1;
    int b0 = n0 / 36, p0 = n0 % 36, b1 = n1 / 36, p1 = n1 % 36;
    int rb0 = ((b0 * 20 + (p0 / 6) * 2) * 20 + (p0 % 6) * 2) * 256 + e0;
    int rb1 = ((b1 * 20 + (p1 / 6) * 2) * 20 + (p1 % 6) * 2) * 256 + e1;
    unsigned short* dAh0 = &sAh[idx0 * 8]; unsigned short* dAh1 = &sAh[idx1 * 8];
    unsigned short* dAl0 = &sAl[idx0 * 8]; unsigned short* dAl1 = &sAl[idx1 * 8];
    unsigned short* dB0  = &sB[idx0 * 8];  unsigned short* dB1  = &sB[idx1 * 8];

    int wid = tid >> 6, lane = tid & 63;
    int wr = wid >> 1, wc = wid & 1;
    int fr = lane & 15, kg = (lane >> 4) * 8;

    int offA[2][2], offB[2][2];
    #pragma unroll
    for (int i = 0; i < 2; ++i) {
        int ra = wr * 32 + i * 16 + fr;
        int rb = wc * 32 + i * 16 + fr;
        #pragma unroll
        for (int k2 = 0; k2 < 2; ++k2) {
            offA[i][k2] = ra * 64 + ((k2 * 32 + kg) ^ ((ra & 7) << 3));
            offB[i][k2] = rb * 64 + ((k2 * 32 + kg) ^ ((rb & 7) << 3));
        }
    }

    f32x4 acc[2][2] = {};
    for (int c = 0; c < NCHUNK; ++c) {
        int g = ks * NCHUNK + c;
        int kw = g >> 2;
        int koff = ((kw / 9) * 20 + (kw % 9)) * 256 + (g & 3) * 64;
        int aoff = c * 64;
        async16(dAh0, gAh0 + aoff); async16(dAh1, gAh1 + aoff);
        async16(dAl0, gAl0 + aoff); async16(dAl1, gAl1 + aoff);
        async16(dB0,  spk + rb0 + koff); async16(dB1, spk + rb1 + koff);
        __syncthreads();
        bf16x8 ah[2][2], al[2][2], bv[2][2];
        #pragma unroll
        for (int i = 0; i < 2; ++i)
            #pragma unroll
            for (int k2 = 0; k2 < 2; ++k2) {
                ah[i][k2] = *(const bf16x8*)&sAh[offA[i][k2]];
                al[i][k2] = *(const bf16x8*)&sAl[offA[i][k2]];
                bv[i][k2] = *(const bf16x8*)&sB[offB[i][k2]];
            }
        #pragma unroll
        for (int k2 = 0; k2 < 2; ++k2)
            #pragma unroll
            for (int i = 0; i < 2; ++i)
                #pragma unroll
                for (int jj = 0; jj < 2; ++jj) {
                    acc[i][jj] = __builtin_amdgcn_mfma_f32_16x16x32_bf16(ah[i][k2], bv[jj][k2], acc[i][jj], 0, 0, 0);
                    acc[i][jj] = __builtin_amdgcn_mfma_f32_16x16x32_bf16(al[i][k2], bv[jj][k2], acc[i][jj], 0, 0, 0);
                }
        __syncthreads();
    }
    int colb = lane & 15, rb4 = (lane >> 4) * 4;
    float* Co = Cp + (size_t)ks * (MM * NN);
    #pragma unroll
    for (int i = 0; i < 2; ++i)
        #pragma unroll
        for (int jj = 0; jj < 2; ++jj) {
            int gm = tm * 64 + wr * 32 + i * 16 + rb4;
            int gn = tn * 64 + wc * 32 + jj * 16 + colb;
            #pragma unroll
            for (int q = 0; q < 4; ++q)
                Co[(size_t)(gm + q) * NN + gn] = acc[i][jj][q];
        }
}

// ---------------- split-K reduce + prim membrane update ----------------
__global__ void k_primmem(const float* __restrict__ Cp, const float* __restrict__ pb,
                          float* __restrict__ pmem) {
    int e = blockIdx.x * 256 + threadIdx.x;
    if (e >= PRIM_ELEMS) return;
    int b = e / 9216, j = e % 9216;
    int oc = j / 36, pos = j % 36;
    int n = b * 36 + pos;
    float s = 0.f;
    #pragma unroll
    for (int ks = 0; ks < KSPLIT; ++ks) s += Cp[(size_t)ks * (MM * NN) + oc * NN + n];
    s += pb[oc];
    float m = pmem[e];
    float ps = (m > THRESH) ? THRESH : 0.f;
    pmem[e] = (m - ps) * DECAY + s;
}

// ---------------- dig: 4 routes x 8 batches per block (1152 blocks) ----------------
__global__ __launch_bounds__(320) void k_dig(const float* __restrict__ pmem,
                                             const float* __restrict__ W,
                                             const float* __restrict__ bias,
                                             const float* __restrict__ bij,
                                             float* __restrict__ dmem,
                                             uint8_t* __restrict__ age,
                                             float* __restrict__ sjp) {
    __shared__ float ps[256];   // [r(4)][bl(8)][i(8)]
    int r0 = blockIdx.x * 4;
    int by = blockIdx.y;        // batch octet
    int tid = threadIdx.x;
    for (int l = tid; l < 256; l += 320) {
        int r = l >> 6, bl = (l >> 3) & 7, i = l & 7;
        float v = pmem[(by * 8 + bl) * 9216 + (r0 + r) * 8 + i];
        ps[l] = (v > THRESH) ? 1.f : 0.f;
    }
    __syncthreads();
    int co = tid % 160, bh = tid / 160;
    int c = co >> 4, o = co & 15;
    float bo = bias[o];
    float sacc[4] = {0.f, 0.f, 0.f, 0.f};
    for (int r = 0; r < 4; ++r) {
        int rr = r0 + r;
        const float* wp = W + ((size_t)((rr * 10 + c) * 16 + o)) * 8;
        f32x4 w0 = *(const f32x4*)wp;
        f32x4 w1 = *(const f32x4*)(wp + 4);
        float bv = bij[rr * 10 + c];
        #pragma unroll
        for (int bb = 0; bb < 4; ++bb) {
            int bl = bh * 4 + bb;
            const float* p8 = &ps[(r * 8 + bl) * 8];
            f32x4 pa = *(const f32x4*)p8;
            f32x4 pc = *(const f32x4*)(p8 + 4);
            float u = bo + w0.x * pa.x + w0.y * pa.y + w0.z * pa.z + w0.w * pa.w
                         + w1.x * pc.x + w1.y * pc.y + w1.z * pc.z + w1.w * pc.w;
            size_t idx = ((size_t)((by * 8 + bl) * 1152 + rr)) * 160 + co;
            float m = dmem[idx];
            float psv = (m > THRESH) ? THRESH : 0.f;
            m = (m - psv) * DECAY + u;
            dmem[idx] = m;
            bool s = m > THRESH;
            if (s) sacc[bb] += bv;
            uint8_t a = age[idx];
            age[idx] = s ? (uint8_t)0 : (a == 255 ? (uint8_t)255 : (uint8_t)(a + 1));
        }
    }
    size_t pbase = ((size_t)(by * 288 + blockIdx.x)) * 1280;
    #pragma unroll
    for (int bb = 0; bb < 4; ++bb)
        sjp[pbase + (bh * 4 + bb) * 160 + co] = sacc[bb];
}

// ---------------- dig2a: reduce sjp partials (k-sliced, atomic) ----------------
__global__ void k_dig2a(const float* __restrict__ sjp, float* __restrict__ sj) {
    int e = blockIdx.x * 256 + threadIdx.x;   // 0..5119
    int y = e / 1280, rem = e % 1280;
    int x0 = blockIdx.y * 24;
    float a = 0.f;
    #pragma unroll 8
    for (int x = x0; x < x0 + 24; ++x)
        a += sjp[((size_t)(y * 288 + x)) * 1280 + rem];
    atomicAdd(&sj[e], a);
}

// ---------------- dig2b: dig2 membrane + out_mem ----------------
__global__ void k_dig2b(const float* __restrict__ sj, float* __restrict__ d2mem,
                        float* __restrict__ omem) {
    int e = blockIdx.x * 256 + threadIdx.x;
    if (e >= B_ * 160) return;
    float s = sj[e];
    float m = d2mem[e];
    float ps = (m > THRESH) ? THRESH : 0.f;
    d2mem[e] = (m - ps) * DECAY + s;
    omem[e] += s;
}

// ---------------- b_ij update ----------------
__global__ void k_bij(const uint8_t* __restrict__ age, const float* __restrict__ d2mem,
                      float* __restrict__ bij) {
    int g = blockIdx.x * 256 + threadIdx.x;
    if (g >= RR * 160) return;
    int r = g / 160, co = g % 160, c = co / 16, o = co & 15;
    const float dtr = expf(-1.0f / 1.5f);
    float tab[5];
    tab[0] = 1.f;
    #pragma unroll
    for (int k = 1; k < 5; ++k) tab[k] = tab[k - 1] * dtr;
    float acc = 0.f;
    for (int b = 0; b < B_; ++b) {
        uint8_t a = age[(size_t)b * (RR * 160) + g];
        float tv = (a > 4) ? 0.f : tab[a];
        float d2 = (d2mem[b * 160 + co] > THRESH) ? 1.f : 0.f;
        acc += (tv - 0.1f) * d2;
    }
    #pragma unroll
    for (int off = 1; off < 16; off <<= 1) acc += __shfl_xor(acc, off);
    if (o == 0) {
        float bo = bij[r * 10 + c];
        bo = fminf(fmaxf(bo, -0.05f), 1.0f);
        bij[r * 10 + c] = bo + 0.0008f * (acc * (1.0f / 32.0f));
    }
}

// ---------------- final: classes ----------------
__global__ void k_out(const float* __restrict__ omem, float* __restrict__ out) {
    int i = blockIdx.x * 64 + threadIdx.x;
    if (i >= B_ * CC) return;
    int b = i / 10, c = i % 10;
    float s = 0.f;
    #pragma unroll
    for (int o = 0; o < 16; ++o) {
        float v = omem[b * 160 + c * 16 + o] / 5.0f;
        s += v * v;
    }
    out[i] = sqrtf(s);
}

extern "C" void kernel_launch(void* const* d_in, const int* in_sizes, int n_in,
                              void* d_out, int out_size, void* d_ws, size_t ws_size,
                              hipStream_t stream) {
    const float* data   = (const float*)d_in[0];
    const float* conv_w = (const float*)d_in[1];
    const float* conv_b = (const float*)d_in[2];
    const float* prim_w = (const float*)d_in[3];
    const float* prim_b = (const float*)d_in[4];
    const float* W      = (const float*)d_in[5];
    const float* bias   = (const float*)d_in[6];
    float* out = (float*)d_out;

    char* ws = (char*)d_ws;
    size_t off = 0;
    auto alloc = [&](size_t bytes) {
        void* p = ws + off;
        off = (off + bytes + 255) & ~(size_t)255;
        return p;
    };
    float*          conv_out = (float*)alloc((size_t)CONV_ELEMS * 4);
    float*          conv_mem = (float*)alloc((size_t)CONV_ELEMS * 4);
    unsigned short* conv_spk = (unsigned short*)alloc((size_t)CONV_ELEMS * 2);
    float*          prim_mem = (float*)alloc((size_t)PRIM_ELEMS * 4);
    float*          dig_mem  = (float*)alloc((size_t)DIG_ELEMS * 4);
    float*          dig2_mem = (float*)alloc(5120 * 4);
    float*          out_mem  = (float*)alloc(5120 * 4);
    float*          sj       = (float*)alloc(5120 * 4);
    float*          sjp      = (float*)alloc((size_t)1152 * 1280 * 4);
    uint8_t*        age      = (uint8_t*)alloc(DIG_ELEMS);
    float*          bij      = (float*)alloc(RR * CC * 4);
    unsigned short* Ahi      = (unsigned short*)alloc((size_t)MM * KK * 2);
    unsigned short* Alo      = (unsigned short*)alloc((size_t)MM * KK * 2);
    float*          Cp       = (float*)alloc((size_t)KSPLIT * MM * NN * 4);

    hipMemsetAsync(conv_mem, 0, (size_t)CONV_ELEMS * 4, stream);
    hipMemsetAsync(prim_mem, 0, (size_t)PRIM_ELEMS * 4, stream);
    hipMemsetAsync(dig_mem, 0, (size_t)DIG_ELEMS * 4, stream);
    hipMemsetAsync(dig2_mem, 0, 5120 * 4, stream);
    hipMemsetAsync(out_mem, 0, 5120 * 4, stream);
    hipMemsetAsync(age, 0xFF, DIG_ELEMS, stream);

    k_init_bij<<<(RR * CC + 255) / 256, 256, 0, stream>>>(bij);
    k_conv1<<<dim3(32, 16), 320, 0, stream>>>(data, conv_w, conv_b, conv_out);
    k_wsplit<<<MM, 256, 0, stream>>>(prim_w, Ahi, Alo);

    for (int t = 0; t < TSTEPS; ++t) {
        k_convmem<<<(CONV_ELEMS / 4 + 255) / 256, 256, 0, stream>>>(conv_mem, conv_out, conv_spk);
        k_gemm<<<8 * 162, 256, 0, stream>>>(Ahi, Alo, conv_spk, Cp);
        k_primmem<<<(PRIM_ELEMS + 255) / 256, 256, 0, stream>>>(Cp, prim_b, prim_mem);
        hipMemsetAsync(sj, 0, 5120 * 4, stream);
        k_dig<<<dim3(288, 4), 320, 0, stream>>>(prim_mem, W, bias, bij, dig_mem, age, sjp);
        k_dig2a<<<dim3(20, 12), 256, 0, stream>>>(sjp, sj);
        k_dig2b<<<20, 256, 0, stream>>>(sj, dig2_mem, out_mem);
        k_bij<<<(RR * 160 + 255) / 256, 256, 0, stream>>>(age, dig2_mem, bij);
    }
    k_out<<<(B_ * CC + 63) / 64, 64, 0, stream>>>(out_mem, out);
}